// Round 8
// baseline (208.518 us; speedup 1.0000x reference)
//
#include <hip/hip_runtime.h>
#include <hip/hip_bf16.h>

typedef __attribute__((ext_vector_type(8)))  short s8v;   // 8 bf16
typedef __attribute__((ext_vector_type(4)))  float f4v;   // 16x16 C/D
typedef _Float16 h4 __attribute__((ext_vector_type(4)));  // 4 f16

constexpr int Dd   = 256;
constexpr int Nn   = 64;
constexpr int NCn  = 128;
constexpr int DDn  = 65536;
constexpr int PPn  = 4 * DDn;
constexpr float EPSf = 1.1920929e-07f;

__device__ __forceinline__ float sigm(float x){ return 1.0f/(1.0f + expf(-x)); }
__device__ __forceinline__ float silu_(float x){ return x * sigm(x); }

__device__ __forceinline__ unsigned short f2b(float x){
    __hip_bfloat16 b = __float2bfloat16(x);
    unsigned short u; __builtin_memcpy(&u, &b, 2); return u;
}
__device__ __forceinline__ float b2f(unsigned short u){
    __hip_bfloat16 b; __builtin_memcpy(&b, &u, 2); return __bfloat162float(b);
}
__device__ __forceinline__ unsigned short f2hu(float x){
    _Float16 h = (_Float16)x;
    unsigned short u; __builtin_memcpy(&u, &h, 2); return u;
}
__device__ __forceinline__ float hu2f(unsigned short u){
    _Float16 h; __builtin_memcpy(&h, &u, 2); return (float)h;
}
__device__ __forceinline__ h4 ldh4(const unsigned short* p){
    h4 r; __builtin_memcpy(&r, p, 8); return r;
}

__device__ __forceinline__ float block_sum(float v, float* red){   // 256 thr
    #pragma unroll
    for (int off = 32; off; off >>= 1) v += __shfl_down(v, off, 64);
    if ((threadIdx.x & 63) == 0) red[threadIdx.x >> 6] = v;
    __syncthreads();
    float r = red[0] + red[1] + red[2] + red[3];
    __syncthreads();
    return r;
}

// 16x256 @ 256x16 slice: A row-major [c][k] chunk tile, B [n][k] rows n0+m16
__device__ __forceinline__ f4v mm_core(const unsigned short* __restrict__ Arow,
                                       const unsigned short* __restrict__ Brow){
    s8v a[8], b[8];
    #pragma unroll
    for (int i = 0; i < 8; ++i) a[i] = *(const s8v*)(Arow + i*32);
    #pragma unroll
    for (int i = 0; i < 8; ++i) b[i] = *(const s8v*)(Brow + i*32);
    f4v acc = {0.f,0.f,0.f,0.f};
    #pragma unroll
    for (int i = 0; i < 8; ++i)
        acc = __builtin_amdgcn_mfma_f32_16x16x32_bf16(a[i], b[i], acc, 0, 0, 0);
    return acc;
}

// ---- merged weight prep: z 0..5 tiled transpose fp32->bf16, z 6..8 cast-copy ----
__global__ __launch_bounds__(256) void ktw(const float* __restrict__ Wq,
        const float* __restrict__ Wkv, const float* __restrict__ W0,
        const float* __restrict__ W1, const float* __restrict__ W2,
        const float* __restrict__ W3, unsigned short* __restrict__ WTb,
        unsigned short* __restrict__ WqTb, unsigned short* __restrict__ WkvTb,
        unsigned short* __restrict__ Wb){
    int z = blockIdx.z;
    if (z >= 6){
        const float* S = (z==6)?W1:(z==7)?W2:W3;
        size_t idx = (((size_t)blockIdx.y*8 + blockIdx.x)*256 + threadIdx.x)*2;
        float2 v = *(const float2*)(S + idx);
        ushort2 u; u.x = f2b(v.x); u.y = f2b(v.y);
        *(ushort2*)(Wb + (size_t)(z-6)*DDn + idx) = u;
        return;
    }
    __shared__ float tl[32][33];
    if (z != 5 && blockIdx.y >= 8) return;
    const float* S; unsigned short* T; int C;
    if (z < 4){ S = (z==0)?W0:(z==1)?W1:(z==2)?W2:W3; T = WTb + (size_t)z*DDn; C = 256; }
    else if (z == 4){ S = Wq; T = WqTb; C = 256; }
    else { S = Wkv; T = WkvTb; C = 512; }
    int k0 = blockIdx.x*32, j0 = blockIdx.y*32;
    int tx = threadIdx.x & 31, ty = threadIdx.x >> 5;
    #pragma unroll
    for (int p = 0; p < 4; ++p)
        tl[ty + 8*p][tx] = S[(size_t)(k0 + ty + 8*p)*C + j0 + tx];
    __syncthreads();
    #pragma unroll
    for (int p = 0; p < 4; ++p)
        T[(size_t)(j0 + ty + 8*p)*256 + k0 + tx] = f2b(tl[tx][ty + 8*p]);
}

// ---- per-token norm, scatter sn + shifted rn ----
__global__ __launch_bounds__(256) void knorm(const float* __restrict__ seq,
        const float* __restrict__ wsn, const float* __restrict__ wrn,
        unsigned short* __restrict__ snb, unsigned short* __restrict__ rnb){
    __shared__ float red[4];
    int t = blockIdx.x, d = threadIdx.x;
    int b = t >> 10, tl = t & 1023, g = t >> 4, c = tl & 15;
    float x = seq[(size_t)t*256 + d];
    float ss = block_sum(x*x, red);
    float xr = x * rsqrtf(ss*(1.f/256.f) + EPSf);
    snb[(size_t)g*4096 + c*256 + d] = f2b(xr*wsn[d]);
    if (tl >= 15){
        int tl2 = tl - 15, g2 = b*64 + (tl2 >> 4), c2 = tl2 & 15;
        rnb[(size_t)g2*4096 + c2*256 + d] = f2b(xr*wrn[d]);
    }
    if (tl >= 1009)
        rnb[(size_t)g*4096 + c*256 + d] = 0;
}

// ---- gates from bf16 sn chunk means ----
__global__ __launch_bounds__(256) void kgates(const unsigned short* __restrict__ snb,
        const float* __restrict__ wa, const float* __restrict__ wm,
        const float* __restrict__ wdk, float* __restrict__ lrg,
        float* __restrict__ momg, float* __restrict__ decg){
    __shared__ float red[4];
    int g = blockIdx.x, d = threadIdx.x;
    float a = 0.f;
    #pragma unroll
    for (int c = 0; c < 16; ++c) a += b2f(snb[(size_t)g*4096 + c*256 + d]);
    float cm = a * (1.f/16.f);
    float da = block_sum(cm*wa[d], red);
    float dm = block_sum(cm*wm[d], red);
    float dc = block_sum(cm*wdk[d], red);
    if (d == 0){ lrg[g] = sigm(da); momg[g] = sigm(dm); decg[g] = sigm(dc); }
}

// ---- kv projection: K -> xb0 (bf16) + XT0 (f16 transposed); V -> vb (f16) ----
__global__ __launch_bounds__(256, 1) void kproj(const unsigned short* __restrict__ snb,
        const unsigned short* __restrict__ WkvTb, unsigned short* __restrict__ xb0,
        unsigned short* __restrict__ XT0, unsigned short* __restrict__ vb){
    int lane = threadIdx.x & 63, w = threadIdx.x >> 6;
    int m16 = lane & 15, q16 = lane >> 4;
    int g = blockIdx.y, n0 = blockIdx.x*64 + w*16;        // 0..511
    f4v acc = mm_core(snb + (size_t)g*4096 + m16*256 + q16*8,
                      WkvTb + (size_t)(n0 + m16)*256 + q16*8);
    if (n0 < 256){
        ushort4 t4;
        #pragma unroll
        for (int r = 0; r < 4; ++r){
            xb0[(size_t)g*4096 + (4*q16 + r)*256 + n0 + m16] = f2b(acc[r]);
            ((unsigned short*)&t4)[r] = f2hu(acc[r]);
        }
        *(ushort4*)(XT0 + ((size_t)g*256 + n0 + m16)*16 + q16*4) = t4;
    } else {
        #pragma unroll
        for (int r = 0; r < 4; ++r)
            vb[(size_t)g*4096 + (4*q16 + r)*256 + (n0 - 256) + m16] = f2hu(acc[r]);
    }
}

// ---- fwd layer: h = x@W; store silu(h) (bf16 + f16-T) and dsilu(h) (f16) ----
__global__ __launch_bounds__(256, 1) void kfwd(const unsigned short* __restrict__ Xin,
        const unsigned short* __restrict__ Wt, unsigned short* __restrict__ Xout,
        unsigned short* __restrict__ XTl, unsigned short* __restrict__ dsb){
    int lane = threadIdx.x & 63, w = threadIdx.x >> 6;
    int m16 = lane & 15, q16 = lane >> 4;
    int g = blockIdx.y, n0 = blockIdx.x*64 + w*16;
    f4v acc = mm_core(Xin + (size_t)g*4096 + m16*256 + q16*8,
                      Wt + (size_t)(n0 + m16)*256 + q16*8);
    ushort4 t4;
    #pragma unroll
    for (int r = 0; r < 4; ++r){
        float h = acc[r], s = sigm(h);
        float sl = h*s, dv = s*(1.f + h*(1.f - s));
        size_t ad = (size_t)g*4096 + (4*q16 + r)*256 + n0 + m16;
        Xout[ad] = f2b(sl);
        dsb[ad]  = f2hu(dv);
        ((unsigned short*)&t4)[r] = f2hu(sl);
    }
    *(ushort4*)(XTl + ((size_t)g*256 + n0 + m16)*16 + q16*4) = t4;
}

// ---- pred layer: G'3 = sc*(x3@W3 - V) -> gb (bf16) + GT3 (f16-T) ----
__global__ __launch_bounds__(256, 1) void kpred(const unsigned short* __restrict__ Xin,
        const unsigned short* __restrict__ Wt, const unsigned short* __restrict__ vb,
        const float* __restrict__ lrg, unsigned short* __restrict__ Gout,
        unsigned short* __restrict__ GT3){
    int lane = threadIdx.x & 63, w = threadIdx.x >> 6;
    int m16 = lane & 15, q16 = lane >> 4;
    int g = blockIdx.y, n0 = blockIdx.x*64 + w*16;
    f4v acc = mm_core(Xin + (size_t)g*4096 + m16*256 + q16*8,
                      Wt + (size_t)(n0 + m16)*256 + q16*8);
    float sc = -2.f * lrg[g] * (1.f/256.f);
    ushort4 t4;
    #pragma unroll
    for (int r = 0; r < 4; ++r){
        size_t ad = (size_t)g*4096 + (4*q16 + r)*256 + n0 + m16;
        float gv = sc * (acc[r] - hu2f(vb[ad]));
        Gout[ad] = f2b(gv);
        ((unsigned short*)&t4)[r] = f2hu(gv);
    }
    *(ushort4*)(GT3 + ((size_t)g*256 + n0 + m16)*16 + q16*4) = t4;
}

// ---- bwd dgrad: G' = (Gin @ W^T) * dsb; -> Gout (bf16, optional) + GTo (f16-T) ----
__global__ __launch_bounds__(256, 1) void kbwd(const unsigned short* __restrict__ Gin,
        const unsigned short* __restrict__ Wrm, const unsigned short* __restrict__ dsb,
        unsigned short* __restrict__ Gout, unsigned short* __restrict__ GTo){
    int lane = threadIdx.x & 63, w = threadIdx.x >> 6;
    int m16 = lane & 15, q16 = lane >> 4;
    int g = blockIdx.y, n0 = blockIdx.x*64 + w*16;
    f4v acc = mm_core(Gin + (size_t)g*4096 + m16*256 + q16*8,
                      Wrm + (size_t)(n0 + m16)*256 + q16*8);
    ushort4 t4;
    #pragma unroll
    for (int r = 0; r < 4; ++r){
        size_t ad = (size_t)g*4096 + (4*q16 + r)*256 + n0 + m16;
        float gv = acc[r] * hu2f(dsb[ad]);
        if (Gout) Gout[ad] = f2b(gv);
        ((unsigned short*)&t4)[r] = f2hu(gv);
    }
    *(ushort4*)(GTo + ((size_t)g*256 + n0 + m16)*16 + q16*4) = t4;
}

// ---- fused outer-product + scans -> updates (bf16) ----
// A = X^T (m = d_in), B = G^T (n = d_out): D[d_in][d_out]; store [out][in] ushort4
__global__ __launch_bounds__(64, 1) void kupd(const unsigned short* __restrict__ XT,
        const unsigned short* __restrict__ GT, const float* __restrict__ momg,
        const float* __restrict__ decg, unsigned short* __restrict__ supb){
    int lane = threadIdx.x, m16 = lane & 15, q16 = lane >> 4;
    int l = blockIdx.z & 3, b = blockIdx.z >> 2;
    int d0 = blockIdx.x*16, o0 = blockIdx.y*16;
    const unsigned short* xbase = XT + (((size_t)l*128 + b*64)*256 + d0 + m16)*16 + q16*4;
    const unsigned short* gbase = GT + (((size_t)l*128 + b*64)*256 + o0 + m16)*16 + q16*4;
    float ms[4] = {0,0,0,0}, us[4] = {0,0,0,0};
    h4 xa = ldh4(xbase);
    h4 gb = ldh4(gbase);
    for (int n = 0; n < 64; ++n){
        int gg = b*64 + n;
        h4 xan, gbn;
        if (n < 63){
            xan = ldh4(xbase + (size_t)(n+1)*4096);
            gbn = ldh4(gbase + (size_t)(n+1)*4096);
        }
        f4v z = {0.f,0.f,0.f,0.f};
        f4v s = __builtin_amdgcn_mfma_f32_16x16x16f16(xa, gb, z, 0, 0, 0);
        float mo = momg[gg], de = 1.f - decg[gg];
        ushort4 u4;
        #pragma unroll
        for (int r = 0; r < 4; ++r){
            ms[r] = mo*ms[r] + s[r];
            us[r] = de*us[r] + ms[r];
            ((unsigned short*)&u4)[r] = f2b(us[r]);
        }
        *(ushort4*)(supb + ((size_t)gg*4 + l)*DDn + (size_t)(o0 + m16)*256
                    + d0 + q16*4) = u4;
        xa = xan; gb = gbn;
    }
}

// ---- one retrieval MLP layer, streaming, no barriers, no LDS ----
// mode 0: silu->bf16 Xout; 2: no act (q-proj)
__global__ __launch_bounds__(256, 1) void klayer(const unsigned short* __restrict__ Xin,
        const unsigned short* __restrict__ Wt, const unsigned short* __restrict__ supb,
        int l, unsigned short* __restrict__ Xout, int mode){
    int lane = threadIdx.x & 63, w = threadIdx.x >> 6;
    int m16 = lane & 15, q16 = lane >> 4;
    int g = blockIdx.y, n0 = blockIdx.x*64 + w*16;
    s8v a[8];
    const unsigned short* ar = Xin + (size_t)g*4096 + m16*256 + q16*8;
    #pragma unroll
    for (int i = 0; i < 8; ++i) a[i] = *(const s8v*)(ar + i*32);
    f4v acc = {0.f,0.f,0.f,0.f};
    const unsigned short* bw = Wt + (size_t)(n0 + m16)*256 + q16*8;
    #pragma unroll
    for (int i = 0; i < 8; ++i){
        s8v b = *(const s8v*)(bw + i*32);
        acc = __builtin_amdgcn_mfma_f32_16x16x32_bf16(a[i], b, acc, 0, 0, 0);
    }
    if (supb){
        const unsigned short* bu = supb + (size_t)l*DDn + (size_t)g*PPn
                                   + (size_t)(n0 + m16)*256 + q16*8;
        #pragma unroll
        for (int i = 0; i < 8; ++i){
            s8v b = *(const s8v*)(bu + i*32);
            acc = __builtin_amdgcn_mfma_f32_16x16x32_bf16(a[i], b, acc, 0, 0, 0);
        }
    }
    #pragma unroll
    for (int r = 0; r < 4; ++r){
        float v = (mode == 0) ? silu_(acc[r]) : acc[r];
        Xout[(size_t)g*4096 + (4*q16 + r)*256 + n0 + m16] = f2b(v);
    }
}

// ---- final fast-weight layer + post rmsnorm + shift + zero rows, fused ----
__global__ __launch_bounds__(256, 1) void klast(const unsigned short* __restrict__ Xin,
        const unsigned short* __restrict__ Wt, const unsigned short* __restrict__ supb,
        const float* __restrict__ wpost, float* __restrict__ out){
    __shared__ float red[4][16];
    __shared__ float rs[16];
    int tid = threadIdx.x, w = tid >> 6, lane = tid & 63;
    int m16 = lane & 15, q16 = lane >> 4;
    int g = blockIdx.x, b = g >> 6, nl = g & 63;
    s8v a[8];
    const unsigned short* ar = Xin + (size_t)g*4096 + m16*256 + q16*8;
    #pragma unroll
    for (int i = 0; i < 8; ++i) a[i] = *(const s8v*)(ar + i*32);
    f4v acc[4];
    #pragma unroll
    for (int t = 0; t < 4; ++t){
        int n0 = w*64 + t*16;
        f4v ac = {0.f,0.f,0.f,0.f};
        const unsigned short* bw = Wt + (size_t)(n0 + m16)*256 + q16*8;
        const unsigned short* bu = supb + (size_t)3*DDn + (size_t)g*PPn
                                   + (size_t)(n0 + m16)*256 + q16*8;
        #pragma unroll
        for (int i = 0; i < 8; ++i){
            s8v bW = *(const s8v*)(bw + i*32);
            s8v bU = *(const s8v*)(bu + i*32);
            ac = __builtin_amdgcn_mfma_f32_16x16x32_bf16(a[i], bW, ac, 0, 0, 0);
            ac = __builtin_amdgcn_mfma_f32_16x16x32_bf16(a[i], bU, ac, 0, 0, 0);
        }
        acc[t] = ac;
    }
    float part[4] = {0,0,0,0};
    #pragma unroll
    for (int t = 0; t < 4; ++t)
        #pragma unroll
        for (int r = 0; r < 4; ++r) part[r] += acc[t][r]*acc[t][r];
    #pragma unroll
    for (int off = 1; off < 16; off <<= 1)
        #pragma unroll
        for (int r = 0; r < 4; ++r) part[r] += __shfl_xor(part[r], off, 64);
    if (m16 == 0)
        #pragma unroll
        for (int r = 0; r < 4; ++r) red[w][4*q16 + r] = part[r];
    __syncthreads();
    if (tid < 16){
        float s = red[0][tid] + red[1][tid] + red[2][tid] + red[3][tid];
        rs[tid] = rsqrtf(s*(1.f/256.f) + EPSf);
    }
    __syncthreads();
    #pragma unroll
    for (int t = 0; t < 4; ++t){
        int d = w*64 + t*16 + m16;
        float wp = wpost[d];
        #pragma unroll
        for (int r = 0; r < 4; ++r){
            int c = 4*q16 + r;
            int tp = nl*16 + c + 15;
            if (tp < 1024)
                out[((size_t)b*1024 + tp)*256 + d] = acc[t][r]*rs[c]*wp;
        }
    }
    if (nl == 0){
        for (int idx = tid; idx < 15*256; idx += 256)
            out[(size_t)b*262144 + idx] = 0.f;
    }
}

extern "C" void kernel_launch(void* const* d_in, const int* in_sizes, int n_in,
                              void* d_out, int out_size, void* d_ws, size_t ws_size,
                              hipStream_t stream) {
    const float* seq     = (const float*)d_in[0];
    const float* w_store = (const float*)d_in[1];
    const float* w_retr  = (const float*)d_in[2];
    const float* w_post  = (const float*)d_in[3];
    const float* Wq      = (const float*)d_in[4];
    const float* Wkv     = (const float*)d_in[5];
    const float* w_adapt = (const float*)d_in[6];
    const float* w_mom   = (const float*)d_in[7];
    const float* w_decay = (const float*)d_in[8];
    const float* W0      = (const float*)d_in[9];
    const float* W1      = (const float*)d_in[10];
    const float* W2      = (const float*)d_in[11];
    const float* W3      = (const float*)d_in[12];

    const size_t TB = (size_t)NCn*4096;           // 524288 elems (1 token-tile)
    float* lrg   = (float*)d_ws;                  // 128
    float* momg  = lrg + NCn;
    float* decg  = momg + NCn;
    unsigned short* p = (unsigned short*)(decg + NCn + 32);
    unsigned short* snb   = p;            p += TB;
    unsigned short* rnb   = p;            p += TB;
    unsigned short* WTb   = p;            p += 4*(size_t)DDn;
    unsigned short* Wb    = p;            p += 3*(size_t)DDn;
    unsigned short* WqTb  = p;            p += (size_t)DDn;
    unsigned short* WkvTb = p;            p += 2*(size_t)DDn;
    unsigned short* xb0   = p;            p += TB;   // x0 = K
    unsigned short* xb1   = p;            p += TB;
    unsigned short* xb2   = p;            p += TB;
    unsigned short* xb3   = p;            p += TB;
    unsigned short* vb    = p;            p += TB;   // f16
    unsigned short* ds0   = p;            p += TB;   // f16 dsilu(h)
    unsigned short* ds1   = p;            p += TB;
    unsigned short* ds2   = p;            p += TB;
    unsigned short* gbA   = p;            p += TB;   // G' ping-pong bf16
    unsigned short* gbB   = p;            p += TB;
    unsigned short* XT    = p;            p += 4*TB; // f16 transposed x
    unsigned short* GT    = p;            p += 4*TB; // f16 transposed G'
    unsigned short* supb  = p;                       // 33.5M bf16 (67MB)
    unsigned short* xr0 = xb0, *xr1 = xb1;           // dead after kupd

    ktw   <<<dim3(8, 16, 9), 256, 0, stream>>>(Wq, Wkv, W0, W1, W2, W3,
                                               WTb, WqTb, WkvTb, Wb);
    knorm <<<dim3(2048),     256, 0, stream>>>(seq, w_store, w_retr, snb, rnb);
    kgates<<<dim3(NCn),      256, 0, stream>>>(snb, w_adapt, w_mom, w_decay,
                                               lrg, momg, decg);
    kproj <<<dim3(8, NCn), 256, 0, stream>>>(snb, WkvTb, xb0, XT + 0*TB, vb);
    kfwd  <<<dim3(4, NCn), 256, 0, stream>>>(xb0, WTb + 0*(size_t)DDn, xb1, XT + 1*TB, ds0);
    kfwd  <<<dim3(4, NCn), 256, 0, stream>>>(xb1, WTb + 1*(size_t)DDn, xb2, XT + 2*TB, ds1);
    kfwd  <<<dim3(4, NCn), 256, 0, stream>>>(xb2, WTb + 2*(size_t)DDn, xb3, XT + 3*TB, ds2);
    kpred <<<dim3(4, NCn), 256, 0, stream>>>(xb3, WTb + 3*(size_t)DDn, vb, lrg, gbA, GT + 3*TB);
    kbwd  <<<dim3(4, NCn), 256, 0, stream>>>(gbA, Wb + 2*(size_t)DDn, ds2, gbB, GT + 2*TB);
    kbwd  <<<dim3(4, NCn), 256, 0, stream>>>(gbB, Wb + 1*(size_t)DDn, ds1, gbA, GT + 1*TB);
    kbwd  <<<dim3(4, NCn), 256, 0, stream>>>(gbA, Wb + 0*(size_t)DDn, ds0, nullptr, GT + 0*TB);
    kupd  <<<dim3(16, 16, 8), 64, 0, stream>>>(XT, GT, momg, decg, supb);
    klayer<<<dim3(4, NCn), 256, 0, stream>>>(rnb, WqTb, nullptr, 0, xr0, 2);
    klayer<<<dim3(4, NCn), 256, 0, stream>>>(xr0, WTb + 0*(size_t)DDn, supb, 0, xr1, 0);
    klayer<<<dim3(4, NCn), 256, 0, stream>>>(xr1, WTb + 1*(size_t)DDn, supb, 1, xr0, 0);
    klayer<<<dim3(4, NCn), 256, 0, stream>>>(xr0, WTb + 2*(size_t)DDn, supb, 2, xr1, 0);
    klast <<<dim3(NCn),    256, 0, stream>>>(xr1, WTb + 3*(size_t)DDn, supb,
                                             w_post, (float*)d_out);
}